// Round 18
// baseline (116.296 us; speedup 1.0000x reference)
//
#include <hip/hip_runtime.h>
#include <hip/hip_bf16.h>
#include <math.h>

#define D      256
#define N2     8192
#define NHALF  4096
#define TILE   128
#define BK     64
#define NCH    4        // 256 / BK
#define LDW    68       // 136B row stride (B panel): maps r5/r13/r14-verified 0-conflict
#define NTRI   2080     // 64*65/2 triangular tiles (bi <= bj); 2080 = 8 XCDs x 260
#define TPB    512      // 8 waves/block, 2 blocks/CU (r12/r16-verified)

typedef __bf16 bf16x8_t __attribute__((ext_vector_type(8)));
typedef __bf16 bf16x4_t __attribute__((ext_vector_type(4)));
typedef float  f32x4_t  __attribute__((ext_vector_type(4)));

// ---------------- kernel 1: fused normalize + positives + denom/ticket zero --------
__global__ __launch_bounds__(256) void prep_kernel(const float* __restrict__ a,
                                                   const float* __restrict__ b,
                                                   __bf16* __restrict__ zb,
                                                   float* __restrict__ g_pos,
                                                   float* __restrict__ g_denom,
                                                   unsigned* __restrict__ g_t1) {
    const int tid = threadIdx.x;
    const int gt  = blockIdx.x * 256 + tid;
    if (gt < N2) g_denom[gt] = 0.0f;
    if (gt < 65 * 32 + 1) g_t1[gt] = 0u;       // 65 spaced L1 tickets + 1 L2 ticket

    const int w = blockIdx.x * 4 + (tid >> 6);  // pair row in [0, NHALF)
    const int l = tid & 63;
    float4 x = ((const float4*)(a + (size_t)w * D))[l];
    float4 y = ((const float4*)(b + (size_t)w * D))[l];
    float sxx = x.x * x.x + x.y * x.y + x.z * x.z + x.w * x.w;
    float syy = y.x * y.x + y.y * y.y + y.z * y.z + y.w * y.w;
    float sxy = x.x * y.x + x.y * y.y + x.z * y.z + x.w * y.w;
    #pragma unroll
    for (int off = 32; off; off >>= 1) {
        sxx += __shfl_xor(sxx, off, 64);
        syy += __shfl_xor(syy, off, 64);
        sxy += __shfl_xor(sxy, off, 64);
    }
    const float rx = 1.0f / fmaxf(sqrtf(sxx), 1e-8f);
    const float ry = 1.0f / fmaxf(sqrtf(syy), 1e-8f);

    bf16x4_t ox, oy;
    ox[0] = (__bf16)(x.x * rx); ox[1] = (__bf16)(x.y * rx);
    ox[2] = (__bf16)(x.z * rx); ox[3] = (__bf16)(x.w * rx);
    oy[0] = (__bf16)(y.x * ry); oy[1] = (__bf16)(y.y * ry);
    oy[2] = (__bf16)(y.z * ry); oy[3] = (__bf16)(y.w * ry);
    *(bf16x4_t*)(zb + (size_t)w * D + l * 4)           = ox;
    *(bf16x4_t*)(zb + (size_t)(w + NHALF) * D + l * 4) = oy;

    if (l == 0) {
        const float p = sxy * rx * ry;
        g_pos[w]         = p;
        g_pos[w + NHALF] = p;
    }
}

// ---------------- kernel 2: triangular sim, PINNED A-direct + XCD swizzle ----------
// r17 post-mortem: plain A-direct loads got SUNK into compute (VGPR stuck at 52) --
// per-chunk serialized L2 latency, sim 47->55. Main loop is 88% LDS-pipe-bound
// (16 waves x 16 ops x 12cyc = 3072 of 3470 cyc/chunk-round), so A-direct's -37%
// LDS ops is right; the loads just must STAY in registers. Fix: opaque inline-asm
// global_load_dwordx4 (cannot be sunk/re-executed -- r3-proven; r3's failure was a
// 128-reg panel under a 256 cap, here it's 32 regs under 128-cap headroom, demand
// ~100). Compiler doesn't track asm loads in vmcnt, so an explicit vmcnt(0) +
// sched_barrier(0) precedes every __syncthreads (rule #18) -- free, since the
// structure drains there anyway. XCD swizzle kept (r17: FETCH 16.7->12.0 MB).
// Gates: VGPR 84-115 (52 = sunk, WRITE>>6MB = spilled -> revert r16+swizzle).
__global__ __launch_bounds__(TPB, 4) void sim_kernel(const __bf16* __restrict__ zb,
                                                     float* __restrict__ g_denom,
                                                     const float* __restrict__ g_pos,
                                                     unsigned* __restrict__ g_t1,
                                                     float* __restrict__ out) {
    __shared__ __bf16 ldsB[2][TILE * LDW];
    __shared__ float  sw[8];
    __shared__ bool   amLast;

    const int tid    = threadIdx.x;
    const int l      = tid & 63;
    const int lane15 = l & 15;
    const int quad   = l >> 4;
    const int w      = tid >> 6;               // wave 0..7
    const int wr     = (w & 3) * 32;           // wave rows: 32
    const int wc     = (w >> 2) * 64;          // wave cols: 64

    // XCD swizzle + triangular decode: k -> (bi, bj), bi <= bj
    const int bx = blockIdx.x;
    const int k  = (bx & 7) * 260 + (bx >> 3);
    int bi = (int)(64.5f - sqrtf(64.5f * 64.5f - 2.0f * (float)k));
    while ((bi * (129 - bi)) / 2 > k) --bi;
    while (((bi + 1) * (128 - bi)) / 2 <= k) ++bi;
    const int bj   = bi + (k - (bi * (129 - bi)) / 2);
    const bool diag = (bi == bj);

    // B staging map (r13/r14-verified 0 conflicts): row r = t>>2, q = t&3
    const int r = tid >> 2;
    const int q = tid & 3;
    const __bf16* gb = zb + (size_t)(bj * TILE + r) * D + q * 16;
    const int wofs = r * LDW + q * 16;

    bf16x8_t sb0, sb1;
    auto loadB = [&](int c) {
        const int k0 = c * BK;
        sb0 = *(const bf16x8_t*)(gb + k0);
        sb1 = *(const bf16x8_t*)(gb + k0 + 8);
    };
    auto writeB = [&](int buf) {
        *(bf16x8_t*)(&ldsB[buf][wofs])     = sb0;
        *(bf16x8_t*)(&ldsB[buf][wofs + 8]) = sb1;
    };

    // A direct loads, OPAQUE asm (unsinkable): af[mi][ks] from row bi*128+wr+mi*16+lane15
    const __bf16* abase = zb + (size_t)(bi * TILE + wr + lane15) * D + quad * 8;
    auto loadA = [&](int c, bf16x8_t (&af)[2][2]) {
        #pragma unroll
        for (int mi = 0; mi < 2; ++mi) {
            #pragma unroll
            for (int ks = 0; ks < 2; ++ks) {
                const __bf16* p = abase + (size_t)mi * 16 * D + c * BK + ks * 32;
                asm volatile("global_load_dwordx4 %0, %1, off"
                             : "=v"(af[mi][ks]) : "v"(p));
            }
        }
    };

    f32x4_t acc[2][4];
    #pragma unroll
    for (int mi = 0; mi < 2; ++mi)
        #pragma unroll
        for (int nj = 0; nj < 4; ++nj)
            acc[mi][nj] = (f32x4_t){0.f, 0.f, 0.f, 0.f};

    auto compute = [&](int buf, const bf16x8_t (&af)[2][2]) {
        #pragma unroll
        for (int ks = 0; ks < 2; ++ks) {
            bf16x8_t bff[4];
            #pragma unroll
            for (int nj = 0; nj < 4; ++nj)
                bff[nj] = *(const bf16x8_t*)(&ldsB[buf][(wc + nj * 16 + lane15) * LDW + ks * 32 + quad * 8]);
            #pragma unroll
            for (int mi = 0; mi < 2; ++mi)
                #pragma unroll
                for (int nj = 0; nj < 4; ++nj)
                    acc[mi][nj] = __builtin_amdgcn_mfma_f32_16x16x32_bf16(bff[nj], af[mi][ks], acc[mi][nj], 0, 0, 0);
        }
    };

    bf16x8_t afA[2][2], afB[2][2];

    // prologue: chunk 0 -> afA (asm) + ldsB[0]; drain before barrier (asm loads are
    // untracked by the compiler's waitcnt bookkeeping -> explicit vmcnt(0)).
    loadA(0, afA);
    loadB(0);
    writeB(0);
    asm volatile("s_waitcnt vmcnt(0)" ::: "memory");
    __builtin_amdgcn_sched_barrier(0);
    __syncthreads();

    auto step = [&](int c, const bf16x8_t (&afC)[2][2], bf16x8_t (&afN)[2][2], int buf) {
        if (c + 1 < NCH) { loadA(c + 1, afN); loadB(c + 1); }
        compute(buf, afC);
        if (c + 1 < NCH) {
            writeB(buf ^ 1);    // safe: buf^1 readers all passed the prior barrier
            asm volatile("s_waitcnt vmcnt(0)" ::: "memory");   // afN + sb landed
            __builtin_amdgcn_sched_barrier(0);
            __syncthreads();
        }
    };
    step(0, afA, afB, 0);
    step(1, afB, afA, 1);
    step(2, afA, afB, 0);
    step(3, afB, afA, 1);

    // epilogue: e = exp2(acc * 2/ln2); rows -> bi panel; cols (off-diag) -> bj panel
    // acc[mi][nj]: S-row = bi*128+wr+mi*16+lane15, S-col = bj*128+wc+nj*16+quad*4+t
    float rs[2] = {0.f, 0.f};
    float cp[4][4];
    #pragma unroll
    for (int nj = 0; nj < 4; ++nj)
        #pragma unroll
        for (int t = 0; t < 4; ++t) cp[nj][t] = 0.f;

    #pragma unroll
    for (int mi = 0; mi < 2; ++mi) {
        #pragma unroll
        for (int nj = 0; nj < 4; ++nj) {
            const bool dn = diag && (wr + mi * 16 == wc + nj * 16);   // wave-uniform
            #pragma unroll
            for (int t = 0; t < 4; ++t) {
                float e = exp2f(acc[mi][nj][t] * 2.8853900817779268f);
                if (dn && (quad * 4 + t) == lane15) e = 0.0f;
                rs[mi] += e;
                cp[nj][t] += e;                   // only consumed when !diag
            }
        }
    }
    // row sums: reduce 4 quads sharing each row, one atomic per row
    #pragma unroll
    for (int mi = 0; mi < 2; ++mi) {
        rs[mi] += __shfl_xor(rs[mi], 16, 64);
        rs[mi] += __shfl_xor(rs[mi], 32, 64);
    }
    if (l < 16) {
        #pragma unroll
        for (int mi = 0; mi < 2; ++mi)
            atomicAdd(&g_denom[bi * TILE + wr + mi * 16 + l], rs[mi]);
    }
    // column sums via recursive halving (r16-verified): 15 shfl, distributed result,
    // one 64-lane atomicAdd.
    if (!diag) {
        float s8[8], s4[4], s2[2], s;
        #pragma unroll
        for (int i = 0; i < 8; ++i) {
            const float lo = cp[i >> 2][i & 3];
            const float hi = cp[(i + 8) >> 2][(i + 8) & 3];
            const float send = (lane15 & 8) ? lo : hi;
            const float recv = __shfl_xor(send, 8, 64);
            s8[i] = ((lane15 & 8) ? hi : lo) + recv;
        }
        #pragma unroll
        for (int i = 0; i < 4; ++i) {
            const float send = (lane15 & 4) ? s8[i] : s8[i + 4];
            const float recv = __shfl_xor(send, 4, 64);
            s4[i] = ((lane15 & 4) ? s8[i + 4] : s8[i]) + recv;
        }
        #pragma unroll
        for (int i = 0; i < 2; ++i) {
            const float send = (lane15 & 2) ? s4[i] : s4[i + 2];
            const float recv = __shfl_xor(send, 2, 64);
            s2[i] = ((lane15 & 2) ? s4[i + 2] : s4[i]) + recv;
        }
        {
            const float send = (lane15 & 1) ? s2[0] : s2[1];
            const float recv = __shfl_xor(send, 1, 64);
            s = ((lane15 & 1) ? s2[1] : s2[0]) + recv;           // v = lane15
        }
        atomicAdd(&g_denom[bj * TILE + wc + (lane15 >> 2) * 16 + quad * 4 + (lane15 & 3)], s);
    }

    // ---------------- two-level fenceless ticket fin (65 groups x 32, r16-verified) --
    __syncthreads();                 // drains vmcnt for every wave -> adds complete
    if (tid == 0) {
        asm volatile("s_waitcnt vmcnt(0)" ::: "memory");
        unsigned t1 = __hip_atomic_fetch_add(&g_t1[(bx >> 5) * 32], 1u,
                                             __ATOMIC_RELAXED, __HIP_MEMORY_SCOPE_AGENT);
        bool grpLast = (t1 == 31);
        unsigned t2 = 0;
        if (grpLast)
            t2 = __hip_atomic_fetch_add(&g_t1[65 * 32], 1u, __ATOMIC_RELAXED,
                                        __HIP_MEMORY_SCOPE_AGENT);
        amLast = grpLast && (t2 == 64);
    }
    __syncthreads();
    if (!amLast) return;

    float local = 0.0f;
    for (int kk = tid; kk < N2; kk += TPB) {
        float dn = __hip_atomic_load(&g_denom[kk], __ATOMIC_RELAXED,
                                     __HIP_MEMORY_SCOPE_AGENT);
        local += logf(dn) - 2.0f * g_pos[kk];
    }
    #pragma unroll
    for (int off = 32; off; off >>= 1) local += __shfl_xor(local, off, 64);
    if (l == 0) sw[w] = local;
    __syncthreads();
    if (tid == 0) {
        float s = 0.f;
        #pragma unroll
        for (int i = 0; i < 8; ++i) s += sw[i];
        out[0] = s / (float)N2;
    }
}

extern "C" void kernel_launch(void* const* d_in, const int* in_sizes, int n_in,
                              void* d_out, int out_size, void* d_ws, size_t ws_size,
                              hipStream_t stream) {
    const float* emb_i = (const float*)d_in[0];
    const float* emb_j = (const float*)d_in[1];

    __bf16*   zb      = (__bf16*)d_ws;                                 // 4 MB
    float*    g_denom = (float*)((char*)d_ws + (size_t)N2 * D * 2);    // 8192 fp32
    float*    g_pos   = g_denom + N2;                                  // 8192 fp32
    unsigned* g_t1    = (unsigned*)(g_pos + N2);                       // 65*32+1 u32 tickets
    float*    out     = (float*)d_out;

    prep_kernel<<<NHALF / 4, 256, 0, stream>>>(emb_i, emb_j, zb, g_pos, g_denom, g_t1);
    sim_kernel<<<NTRI, TPB, 0, stream>>>(zb, g_denom, g_pos, g_t1, out);
}

// Round 19
// 107.127 us; speedup vs baseline: 1.0856x; 1.0856x over previous
//
#include <hip/hip_runtime.h>
#include <hip/hip_bf16.h>
#include <math.h>

#define D      256
#define N2     8192
#define NHALF  4096
#define TILE   128
#define BK     64
#define NCH    4        // 256 / BK
#define LDW    68       // 136B row stride: r5-verified 0-conflict read+write maps
#define NTRI   2080     // 64*65/2 triangular tiles (bi <= bj); 2080 = 8 XCDs x 260

typedef __bf16 bf16x8_t __attribute__((ext_vector_type(8)));
typedef __bf16 bf16x4_t __attribute__((ext_vector_type(4)));
typedef float  f32x4_t  __attribute__((ext_vector_type(4)));

// ---------------- kernel 1: fused normalize + positives + denom/ticket zero --------
__global__ __launch_bounds__(256) void prep_kernel(const float* __restrict__ a,
                                                   const float* __restrict__ b,
                                                   __bf16* __restrict__ zb,
                                                   float* __restrict__ g_pos,
                                                   float* __restrict__ g_denom,
                                                   unsigned* __restrict__ g_t1) {
    const int tid = threadIdx.x;
    const int gt  = blockIdx.x * 256 + tid;
    if (gt < N2) g_denom[gt] = 0.0f;
    if (gt < 65 * 32 + 1) g_t1[gt] = 0u;       // 65 spaced L1 tickets + 1 L2 ticket

    const int w = blockIdx.x * 4 + (tid >> 6);  // pair row in [0, NHALF)
    const int l = tid & 63;
    float4 x = ((const float4*)(a + (size_t)w * D))[l];
    float4 y = ((const float4*)(b + (size_t)w * D))[l];
    float sxx = x.x * x.x + x.y * x.y + x.z * x.z + x.w * x.w;
    float syy = y.x * y.x + y.y * y.y + y.z * y.z + y.w * y.w;
    float sxy = x.x * y.x + x.y * y.y + x.z * y.z + x.w * y.w;
    #pragma unroll
    for (int off = 32; off; off >>= 1) {
        sxx += __shfl_xor(sxx, off, 64);
        syy += __shfl_xor(syy, off, 64);
        sxy += __shfl_xor(sxy, off, 64);
    }
    const float rx = 1.0f / fmaxf(sqrtf(sxx), 1e-8f);
    const float ry = 1.0f / fmaxf(sqrtf(syy), 1e-8f);

    bf16x4_t ox, oy;
    ox[0] = (__bf16)(x.x * rx); ox[1] = (__bf16)(x.y * rx);
    ox[2] = (__bf16)(x.z * rx); ox[3] = (__bf16)(x.w * rx);
    oy[0] = (__bf16)(y.x * ry); oy[1] = (__bf16)(y.y * ry);
    oy[2] = (__bf16)(y.z * ry); oy[3] = (__bf16)(y.w * ry);
    *(bf16x4_t*)(zb + (size_t)w * D + l * 4)           = ox;
    *(bf16x4_t*)(zb + (size_t)(w + NHALF) * D + l * 4) = oy;

    if (l == 0) {
        const float p = sxy * rx * ry;
        g_pos[w]         = p;
        g_pos[w + NHALF] = p;
    }
}

// ---------------- kernel 2: r5 core (256t, 64x64 wave tiles) x triangle x swizzle --
// r18 post-mortem: A-direct doubles A's L2 traffic (waves w and w+4 share rows) --
// LDS savings fully offset; dead end. Re-audit exposed the real regression: the
// r12/r16 512-thread 32x64-wave-tile geometry needs 128 LDS ops per 128^2x64
// tile-chunk vs the r5 256-thread 64x64-tile geometry's 80 (bigger wave tile = more
// reuse/byte). r5 per-tile = 16.1us/1000 vs r16 22.7. This round recombines ONLY
// verified pieces: r5's byte-identical sim core (66us/4096 tiles, VGPR 88, 0
// conflicts) + triangle decode (r15/16) + XCD swizzle (r17/18: FETCH 16.7->12MB) +
// recursive-halving col epilogue + two-level fenceless tickets (r16; cp[4][4] is
// index-identical). No new mechanisms.
__global__ __launch_bounds__(256, 2) void sim_kernel(const __bf16* __restrict__ zb,
                                                     float* __restrict__ g_denom,
                                                     const float* __restrict__ g_pos,
                                                     unsigned* __restrict__ g_t1,
                                                     float* __restrict__ out) {
    __shared__ __bf16 ldsA[2][TILE * LDW];
    __shared__ __bf16 ldsB[2][TILE * LDW];
    __shared__ float  sw[4];
    __shared__ bool   amLast;

    const int tid    = threadIdx.x;
    const int l      = tid & 63;
    const int lane15 = l & 15;
    const int quad   = l >> 4;
    const int w      = tid >> 6;               // wave 0..3
    const int wr     = (w >> 1) * 64;          // wave row offset in tile
    const int wc     = (w & 1) * 64;           // wave col offset in tile

    // XCD swizzle + triangular decode: k -> (bi, bj), bi <= bj
    const int bx = blockIdx.x;
    const int k  = (bx & 7) * 260 + (bx >> 3);
    int bi = (int)(64.5f - sqrtf(64.5f * 64.5f - 2.0f * (float)k));
    while ((bi * (129 - bi)) / 2 > k) --bi;
    while (((bi + 1) * (128 - bi)) / 2 <= k) ++bi;
    const int bj   = bi + (k - (bi * (129 - bi)) / 2);
    const bool diag = (bi == bj);

    // staging map (r5-verified 0 conflicts): thread t -> row r = t>>1, half = t&1
    const int r    = tid >> 1;
    const int half = tid & 1;
    const __bf16* ga = zb + (size_t)(bi * TILE + r) * D + half * 32;
    const __bf16* gb = zb + (size_t)(bj * TILE + r) * D + half * 32;
    const int wofs = r * LDW + half * 32;

    bf16x8_t sa[4], sb[4];
    auto load_regs = [&](int c) {
        const int k0 = c * BK;
        #pragma unroll
        for (int u = 0; u < 4; ++u) {
            sa[u] = *(const bf16x8_t*)(ga + k0 + u * 8);
            sb[u] = *(const bf16x8_t*)(gb + k0 + u * 8);
        }
    };
    auto write_lds = [&](int buf) {
        #pragma unroll
        for (int u = 0; u < 4; ++u) {
            *(bf16x8_t*)(&ldsA[buf][wofs + u * 8]) = sa[u];
            *(bf16x8_t*)(&ldsB[buf][wofs + u * 8]) = sb[u];
        }
    };

    f32x4_t acc[4][4];
    #pragma unroll
    for (int mi = 0; mi < 4; ++mi)
        #pragma unroll
        for (int nj = 0; nj < 4; ++nj)
            acc[mi][nj] = (f32x4_t){0.f, 0.f, 0.f, 0.f};

    auto compute = [&](int buf) {
        #pragma unroll
        for (int ks = 0; ks < 2; ++ks) {
            bf16x8_t af[4], bff[4];
            #pragma unroll
            for (int mi = 0; mi < 4; ++mi)
                af[mi] = *(const bf16x8_t*)(&ldsA[buf][(wr + mi * 16 + lane15) * LDW + ks * 32 + quad * 8]);
            #pragma unroll
            for (int nj = 0; nj < 4; ++nj)
                bff[nj] = *(const bf16x8_t*)(&ldsB[buf][(wc + nj * 16 + lane15) * LDW + ks * 32 + quad * 8]);
            #pragma unroll
            for (int mi = 0; mi < 4; ++mi)
                #pragma unroll
                for (int nj = 0; nj < 4; ++nj)
                    acc[mi][nj] = __builtin_amdgcn_mfma_f32_16x16x32_bf16(bff[nj], af[mi], acc[mi][nj], 0, 0, 0);
        }
    };

    // prologue: stage chunk 0
    load_regs(0);
    write_lds(0);
    __syncthreads();

    int cur = 0;
    #pragma unroll
    for (int c = 0; c < NCH; ++c) {
        if (c + 1 < NCH) load_regs(c + 1);
        compute(cur);
        if (c + 1 < NCH) {
            write_lds(cur ^ 1);     // safe: buf[cur^1] readers all passed prior barrier
            __syncthreads();
            cur ^= 1;
        }
    }

    // epilogue: e = exp2(acc * 2/ln2); rows -> bi panel; cols (off-diag) -> bj panel
    // acc[mi][nj]: S-row = bi*128+wr+mi*16+lane15, S-col = bj*128+wc+nj*16+quad*4+t
    float rs[4] = {0.f, 0.f, 0.f, 0.f};
    float cp[4][4];
    #pragma unroll
    for (int nj = 0; nj < 4; ++nj)
        #pragma unroll
        for (int t = 0; t < 4; ++t) cp[nj][t] = 0.f;

    #pragma unroll
    for (int mi = 0; mi < 4; ++mi) {
        #pragma unroll
        for (int nj = 0; nj < 4; ++nj) {
            const bool dn = diag && (wr + mi * 16 == wc + nj * 16);   // wave-uniform
            #pragma unroll
            for (int t = 0; t < 4; ++t) {
                float e = exp2f(acc[mi][nj][t] * 2.8853900817779268f);
                if (dn && (quad * 4 + t) == lane15) e = 0.0f;
                rs[mi] += e;
                cp[nj][t] += e;                   // only consumed when !diag
            }
        }
    }
    // row sums: reduce 4 quads sharing each row, one atomic per row
    #pragma unroll
    for (int mi = 0; mi < 4; ++mi) {
        rs[mi] += __shfl_xor(rs[mi], 16, 64);
        rs[mi] += __shfl_xor(rs[mi], 32, 64);
    }
    if (l < 16) {
        #pragma unroll
        for (int mi = 0; mi < 4; ++mi)
            atomicAdd(&g_denom[bi * TILE + wr + mi * 16 + l], rs[mi]);
    }
    // column sums via recursive halving (r16-verified): 15 shfl, distributed result,
    // one 64-lane atomicAdd.
    if (!diag) {
        float s8[8], s4[4], s2[2], s;
        #pragma unroll
        for (int i = 0; i < 8; ++i) {
            const float lo = cp[i >> 2][i & 3];
            const float hi = cp[(i + 8) >> 2][(i + 8) & 3];
            const float send = (lane15 & 8) ? lo : hi;
            const float recv = __shfl_xor(send, 8, 64);
            s8[i] = ((lane15 & 8) ? hi : lo) + recv;
        }
        #pragma unroll
        for (int i = 0; i < 4; ++i) {
            const float send = (lane15 & 4) ? s8[i] : s8[i + 4];
            const float recv = __shfl_xor(send, 4, 64);
            s4[i] = ((lane15 & 4) ? s8[i + 4] : s8[i]) + recv;
        }
        #pragma unroll
        for (int i = 0; i < 2; ++i) {
            const float send = (lane15 & 2) ? s4[i] : s4[i + 2];
            const float recv = __shfl_xor(send, 2, 64);
            s2[i] = ((lane15 & 2) ? s4[i + 2] : s4[i]) + recv;
        }
        {
            const float send = (lane15 & 1) ? s2[0] : s2[1];
            const float recv = __shfl_xor(send, 1, 64);
            s = ((lane15 & 1) ? s2[1] : s2[0]) + recv;           // v = lane15
        }
        atomicAdd(&g_denom[bj * TILE + wc + (lane15 >> 2) * 16 + quad * 4 + (lane15 & 3)], s);
    }

    // ---------------- two-level fenceless ticket fin (65 groups x 32, r16-verified) --
    __syncthreads();                 // drains vmcnt for every wave -> adds complete
    if (tid == 0) {
        asm volatile("s_waitcnt vmcnt(0)" ::: "memory");
        unsigned t1 = __hip_atomic_fetch_add(&g_t1[(bx >> 5) * 32], 1u,
                                             __ATOMIC_RELAXED, __HIP_MEMORY_SCOPE_AGENT);
        bool grpLast = (t1 == 31);
        unsigned t2 = 0;
        if (grpLast)
            t2 = __hip_atomic_fetch_add(&g_t1[65 * 32], 1u, __ATOMIC_RELAXED,
                                        __HIP_MEMORY_SCOPE_AGENT);
        amLast = grpLast && (t2 == 64);
    }
    __syncthreads();
    if (!amLast) return;

    float local = 0.0f;
    for (int kk = tid; kk < N2; kk += 256) {
        float dn = __hip_atomic_load(&g_denom[kk], __ATOMIC_RELAXED,
                                     __HIP_MEMORY_SCOPE_AGENT);
        local += logf(dn) - 2.0f * g_pos[kk];
    }
    #pragma unroll
    for (int off = 32; off; off >>= 1) local += __shfl_xor(local, off, 64);
    if (l == 0) sw[w] = local;
    __syncthreads();
    if (tid == 0) out[0] = (sw[0] + sw[1] + sw[2] + sw[3]) / (float)N2;
}

extern "C" void kernel_launch(void* const* d_in, const int* in_sizes, int n_in,
                              void* d_out, int out_size, void* d_ws, size_t ws_size,
                              hipStream_t stream) {
    const float* emb_i = (const float*)d_in[0];
    const float* emb_j = (const float*)d_in[1];

    __bf16*   zb      = (__bf16*)d_ws;                                 // 4 MB
    float*    g_denom = (float*)((char*)d_ws + (size_t)N2 * D * 2);    // 8192 fp32
    float*    g_pos   = g_denom + N2;                                  // 8192 fp32
    unsigned* g_t1    = (unsigned*)(g_pos + N2);                       // 65*32+1 u32 tickets
    float*    out     = (float*)d_out;

    prep_kernel<<<NHALF / 4, 256, 0, stream>>>(emb_i, emb_j, zb, g_pos, g_denom, g_t1);
    sim_kernel<<<NTRI, 256, 0, stream>>>(zb, g_denom, g_pos, g_t1, out);
}

// Round 20
// 101.132 us; speedup vs baseline: 1.1500x; 1.0593x over previous
//
#include <hip/hip_runtime.h>
#include <hip/hip_bf16.h>
#include <math.h>

#define D      256
#define N2     8192
#define NHALF  4096
#define TILE   128
#define BK     64
#define NCH    8       // 256 / BK
#define LDW    68      // LDS row stride in bf16: r5/r13/r14-verified 0-conflict maps
#define NTRI   2080    // 64*65/2 triangular tiles (bi <= bj); 2080 = 8 XCDs x 260
#define TPB    512     // 8 waves/block, 2 blocks/CU -> 4 waves/SIMD (r16-verified)
#undef NCH
#define NCH    8
// NOTE: r16 used BK=64 with NCH=4? -- no: r16 ran BK=64, NCH=4, TPB=512. Keep that.
#undef NCH
#define NCH    4

typedef __bf16 bf16x8_t __attribute__((ext_vector_type(8)));
typedef __bf16 bf16x4_t __attribute__((ext_vector_type(4)));
typedef float  f32x4_t  __attribute__((ext_vector_type(4)));

// ---------------- kernel 1: fused normalize + positives + denom/ticket zero --------
__global__ __launch_bounds__(256) void prep_kernel(const float* __restrict__ a,
                                                   const float* __restrict__ b,
                                                   __bf16* __restrict__ zb,
                                                   float* __restrict__ g_pos,
                                                   float* __restrict__ g_denom,
                                                   unsigned* __restrict__ g_t1) {
    const int tid = threadIdx.x;
    const int gt  = blockIdx.x * 256 + tid;
    if (gt < N2) g_denom[gt] = 0.0f;
    if (gt < 65 * 32 + 1) g_t1[gt] = 0u;       // 65 spaced L1 tickets + 1 L2 ticket

    const int w = blockIdx.x * 4 + (tid >> 6);  // pair row in [0, NHALF)
    const int l = tid & 63;
    float4 x = ((const float4*)(a + (size_t)w * D))[l];
    float4 y = ((const float4*)(b + (size_t)w * D))[l];
    float sxx = x.x * x.x + x.y * x.y + x.z * x.z + x.w * x.w;
    float syy = y.x * y.x + y.y * y.y + y.z * y.z + y.w * y.w;
    float sxy = x.x * y.x + x.y * y.y + x.z * y.z + x.w * y.w;
    #pragma unroll
    for (int off = 32; off; off >>= 1) {
        sxx += __shfl_xor(sxx, off, 64);
        syy += __shfl_xor(syy, off, 64);
        sxy += __shfl_xor(sxy, off, 64);
    }
    const float rx = 1.0f / fmaxf(sqrtf(sxx), 1e-8f);
    const float ry = 1.0f / fmaxf(sqrtf(syy), 1e-8f);

    bf16x4_t ox, oy;
    ox[0] = (__bf16)(x.x * rx); ox[1] = (__bf16)(x.y * rx);
    ox[2] = (__bf16)(x.z * rx); ox[3] = (__bf16)(x.w * rx);
    oy[0] = (__bf16)(y.x * ry); oy[1] = (__bf16)(y.y * ry);
    oy[2] = (__bf16)(y.z * ry); oy[3] = (__bf16)(y.w * ry);
    *(bf16x4_t*)(zb + (size_t)w * D + l * 4)           = ox;
    *(bf16x4_t*)(zb + (size_t)(w + NHALF) * D + l * 4) = oy;

    if (l == 0) {
        const float p = sxy * rx * ry;
        g_pos[w]         = p;
        g_pos[w + NHALF] = p;
    }
}

// ---------------- kernel 2: r16 sim (byte-identical) + XCD swizzle (1 line) --------
// r19 post-mortem: the 256t "more LDS-efficient" core ran at 2 waves/SIMD -- the
// triangle's latency-bound epilogue had nothing to hide behind (per-tile 7.3us vs
// r16's 5.8). r16's 512t/4-waves-per-SIMD triangle stays the verified best (47.2us).
// This round is a pure single-variable A/B: add the bijective XCD swizzle
// k=(bx&7)*260+(bx>>3) (2080=8x260) to r16. Mechanism: co-dispatched blocks on one
// XCD walk consecutive tiles -> shared bi panels stay in that XCD's L2 (FETCH
// 16.7->12MB, reproduced r17/r19) -> staging becomes L2-hit, shortening the
// stage-drain stall. Everything else byte-identical to r16.
__global__ __launch_bounds__(TPB, 4) void sim_kernel(const __bf16* __restrict__ zb,
                                                     float* __restrict__ g_denom,
                                                     const float* __restrict__ g_pos,
                                                     unsigned* __restrict__ g_t1,
                                                     float* __restrict__ out) {
    __shared__ __bf16 ldsA[2][TILE * LDW];
    __shared__ __bf16 ldsB[2][TILE * LDW];
    __shared__ float  sw[8];
    __shared__ bool   amLast;

    const int tid    = threadIdx.x;
    const int l      = tid & 63;
    const int lane15 = l & 15;
    const int quad   = l >> 4;
    const int w      = tid >> 6;               // wave 0..7
    const int wr     = (w & 3) * 32;           // wave rows: 32
    const int wc     = (w >> 2) * 64;          // wave cols: 64

    // XCD swizzle (the round's single change) + triangular decode
    const int bx = blockIdx.x;
    const int k  = (bx & 7) * 260 + (bx >> 3);
    int bi = (int)(64.5f - sqrtf(64.5f * 64.5f - 2.0f * (float)k));
    while ((bi * (129 - bi)) / 2 > k) --bi;
    while (((bi + 1) * (128 - bi)) / 2 <= k) ++bi;
    const int bj   = bi + (k - (bi * (129 - bi)) / 2);
    const bool diag = (bi == bj);

    // staging map (r13/r14-verified 0 conflicts): row r = t>>2, q = t&3, 16 bf16 at q*16
    const int r = tid >> 2;
    const int q = tid & 3;
    const __bf16* ga = zb + (size_t)(bi * TILE + r) * D + q * 16;
    const __bf16* gb = zb + (size_t)(bj * TILE + r) * D + q * 16;
    const int wofs = r * LDW + q * 16;

    bf16x8_t sa0, sa1, sb0, sb1;
    auto load_regs = [&](int c) {
        const int k0 = c * BK;
        sa0 = *(const bf16x8_t*)(ga + k0);
        sa1 = *(const bf16x8_t*)(ga + k0 + 8);
        sb0 = *(const bf16x8_t*)(gb + k0);
        sb1 = *(const bf16x8_t*)(gb + k0 + 8);
    };
    auto write_lds = [&](int buf) {
        *(bf16x8_t*)(&ldsA[buf][wofs])     = sa0;
        *(bf16x8_t*)(&ldsA[buf][wofs + 8]) = sa1;
        *(bf16x8_t*)(&ldsB[buf][wofs])     = sb0;
        *(bf16x8_t*)(&ldsB[buf][wofs + 8]) = sb1;
    };

    f32x4_t acc[2][4];
    #pragma unroll
    for (int mi = 0; mi < 2; ++mi)
        #pragma unroll
        for (int nj = 0; nj < 4; ++nj)
            acc[mi][nj] = (f32x4_t){0.f, 0.f, 0.f, 0.f};

    auto compute = [&](int buf) {
        #pragma unroll
        for (int ks = 0; ks < 2; ++ks) {
            bf16x8_t af[2], bff[4];
            #pragma unroll
            for (int mi = 0; mi < 2; ++mi)
                af[mi] = *(const bf16x8_t*)(&ldsA[buf][(wr + mi * 16 + lane15) * LDW + ks * 32 + quad * 8]);
            #pragma unroll
            for (int nj = 0; nj < 4; ++nj)
                bff[nj] = *(const bf16x8_t*)(&ldsB[buf][(wc + nj * 16 + lane15) * LDW + ks * 32 + quad * 8]);
            #pragma unroll
            for (int mi = 0; mi < 2; ++mi)
                #pragma unroll
                for (int nj = 0; nj < 4; ++nj)
                    acc[mi][nj] = __builtin_amdgcn_mfma_f32_16x16x32_bf16(bff[nj], af[mi], acc[mi][nj], 0, 0, 0);
        }
    };

    // prologue: stage chunk 0
    load_regs(0);
    write_lds(0);
    __syncthreads();

    int cur = 0;
    #pragma unroll
    for (int c = 0; c < NCH; ++c) {
        if (c + 1 < NCH) load_regs(c + 1);
        compute(cur);
        if (c + 1 < NCH) {
            write_lds(cur ^ 1);     // safe: buf[cur^1] readers all passed prior barrier
            __syncthreads();
            cur ^= 1;
        }
    }

    // epilogue: e = exp2(acc * 2/ln2); rows -> bi panel; cols (off-diag) -> bj panel
    // acc[mi][nj]: S-row = bi*128+wr+mi*16+lane15, S-col = bj*128+wc+nj*16+quad*4+t
    float rs[2] = {0.f, 0.f};
    float cp[4][4];
    #pragma unroll
    for (int nj = 0; nj < 4; ++nj)
        #pragma unroll
        for (int t = 0; t < 4; ++t) cp[nj][t] = 0.f;

    #pragma unroll
    for (int mi = 0; mi < 2; ++mi) {
        #pragma unroll
        for (int nj = 0; nj < 4; ++nj) {
            const bool dn = diag && (wr + mi * 16 == wc + nj * 16);   // wave-uniform
            #pragma unroll
            for (int t = 0; t < 4; ++t) {
                float e = exp2f(acc[mi][nj][t] * 2.8853900817779268f);
                if (dn && (quad * 4 + t) == lane15) e = 0.0f;
                rs[mi] += e;
                cp[nj][t] += e;                   // only consumed when !diag
            }
        }
    }
    // row sums: reduce 4 quads sharing each row, one atomic per row
    #pragma unroll
    for (int mi = 0; mi < 2; ++mi) {
        rs[mi] += __shfl_xor(rs[mi], 16, 64);
        rs[mi] += __shfl_xor(rs[mi], 32, 64);
    }
    if (l < 16) {
        #pragma unroll
        for (int mi = 0; mi < 2; ++mi)
            atomicAdd(&g_denom[bi * TILE + wr + mi * 16 + l], rs[mi]);
    }
    // column sums via recursive halving (r16-verified): 15 shfl, distributed result,
    // one 64-lane atomicAdd.
    if (!diag) {
        float s8[8], s4[4], s2[2], s;
        #pragma unroll
        for (int i = 0; i < 8; ++i) {
            const float lo = cp[i >> 2][i & 3];
            const float hi = cp[(i + 8) >> 2][(i + 8) & 3];
            const float send = (lane15 & 8) ? lo : hi;
            const float recv = __shfl_xor(send, 8, 64);
            s8[i] = ((lane15 & 8) ? hi : lo) + recv;
        }
        #pragma unroll
        for (int i = 0; i < 4; ++i) {
            const float send = (lane15 & 4) ? s8[i] : s8[i + 4];
            const float recv = __shfl_xor(send, 4, 64);
            s4[i] = ((lane15 & 4) ? s8[i + 4] : s8[i]) + recv;
        }
        #pragma unroll
        for (int i = 0; i < 2; ++i) {
            const float send = (lane15 & 2) ? s4[i] : s4[i + 2];
            const float recv = __shfl_xor(send, 2, 64);
            s2[i] = ((lane15 & 2) ? s4[i + 2] : s4[i]) + recv;
        }
        {
            const float send = (lane15 & 1) ? s2[0] : s2[1];
            const float recv = __shfl_xor(send, 1, 64);
            s = ((lane15 & 1) ? s2[1] : s2[0]) + recv;           // v = lane15
        }
        atomicAdd(&g_denom[bj * TILE + wc + (lane15 >> 2) * 16 + quad * 4 + (lane15 & 3)], s);
    }

    // ---------------- two-level fenceless ticket fin (65 groups x 32, r16-verified) --
    __syncthreads();                 // drains vmcnt for every wave -> adds complete
    if (tid == 0) {
        asm volatile("s_waitcnt vmcnt(0)" ::: "memory");
        unsigned t1 = __hip_atomic_fetch_add(&g_t1[(bx >> 5) * 32], 1u,
                                             __ATOMIC_RELAXED, __HIP_MEMORY_SCOPE_AGENT);
        bool grpLast = (t1 == 31);
        unsigned t2 = 0;
        if (grpLast)
            t2 = __hip_atomic_fetch_add(&g_t1[65 * 32], 1u, __ATOMIC_RELAXED,
                                        __HIP_MEMORY_SCOPE_AGENT);
        amLast = grpLast && (t2 == 64);
    }
    __syncthreads();
    if (!amLast) return;

    float local = 0.0f;
    for (int kk = tid; kk < N2; kk += TPB) {
        float dn = __hip_atomic_load(&g_denom[kk], __ATOMIC_RELAXED,
                                     __HIP_MEMORY_SCOPE_AGENT);
        local += logf(dn) - 2.0f * g_pos[kk];
    }
    #pragma unroll
    for (int off = 32; off; off >>= 1) local += __shfl_xor(local, off, 64);
    if (l == 0) sw[w] = local;
    __syncthreads();
    if (tid == 0) {
        float s = 0.f;
        #pragma unroll
        for (int i = 0; i < 8; ++i) s += sw[i];
        out[0] = s / (float)N2;
    }
}

extern "C" void kernel_launch(void* const* d_in, const int* in_sizes, int n_in,
                              void* d_out, int out_size, void* d_ws, size_t ws_size,
                              hipStream_t stream) {
    const float* emb_i = (const float*)d_in[0];
    const float* emb_j = (const float*)d_in[1];

    __bf16*   zb      = (__bf16*)d_ws;                                 // 4 MB
    float*    g_denom = (float*)((char*)d_ws + (size_t)N2 * D * 2);    // 8192 fp32
    float*    g_pos   = g_denom + N2;                                  // 8192 fp32
    unsigned* g_t1    = (unsigned*)(g_pos + N2);                       // 65*32+1 u32 tickets
    float*    out     = (float*)d_out;

    prep_kernel<<<NHALF / 4, 256, 0, stream>>>(emb_i, emb_j, zb, g_pos, g_denom, g_t1);
    sim_kernel<<<NTRI, TPB, 0, stream>>>(zb, g_denom, g_pos, g_t1, out);
}